// Round 14
// baseline (211.026 us; speedup 1.0000x reference)
//
#include <hip/hip_runtime.h>

// WaveConv3d: B=4, C=32, D=H=W=64, LEVEL=2, m=16.
// Stage 1: s[inp][k][b][c][v16] = (1/8) * WHT3( 2x2x2 sums of 4x4x4 block )
// Stage 2+3 FUSED (R14): out = (1/8) * invWHT3_k( sum_i s1*W1 + s2*W2 )
//
// R14: R13's null (contiguous stores == scattered, ~0 delta) killed the
// store-pattern theory for k_inv's ~60us. Fuse mix+inv: per (o,voxel)
// thread, loop k: mix[b] = sum_i s1*W1+s2*W2 (k_mix's exact proven load
// shape), then fold the inverse WHT: acc[b][m] += sign(popcount(k&m))*mix[b].
// Deletes the mixed 16MB round-trip, one dispatch, and k_inv entirely.
// XCD pin: bid = o*16+vblk -> bid%8 = vblk%8 (32 o-blocks share one vblk's
// 2MB s-slice per XCD L2). All acc/mix indexing compile-time.

#define M3 4096        // 16*16*16 voxels
#define KS 524288      // 4*32*M3  : k-stride in s
#define IS 4194304     // 8*KS     : input-stride in s

// R7 k_fwd (proven ~36us warm): 4-stream interleaved loads, strided stores.
__global__ __launch_bounds__(256) void k_fwd(const float* __restrict__ x1,
                                             const float* __restrict__ x2,
                                             float* __restrict__ s) {
  const int tid = blockIdx.x * 256 + threadIdx.x;   // 2048 blocks
  const int v  = tid & 4095;
  const int bc = tid >> 12;          // 0..127  (b*32+c)
  const int z = v & 15, y = (v >> 4) & 15, x = v >> 8;
  const size_t base = ((((size_t)bc * 64 + 4 * x) * 64 + 4 * y) * 64 + 4 * z);
  const float* __restrict__ p10 = x1 + base;
  const float* __restrict__ p11 = x1 + base + 2 * 4096;
  const float* __restrict__ p20 = x2 + base;
  const float* __restrict__ p21 = x2 + base + 2 * 4096;

  float4 a1[2][2], a2[2][2];         // [p][q] float4 partial sums
#pragma unroll
  for (int p = 0; p < 2; ++p)
#pragma unroll
    for (int q = 0; q < 2; ++q) {
      a1[p][q] = make_float4(0.f, 0.f, 0.f, 0.f);
      a2[p][q] = make_float4(0.f, 0.f, 0.f, 0.f);
    }

#pragma unroll
  for (int dp = 0; dp < 2; ++dp) {
#pragma unroll
    for (int hh = 0; hh < 4; ++hh) {
      const int off = (dp * 64 + hh) * 64;
      const float4 f10 = *reinterpret_cast<const float4*>(p10 + off);
      const float4 f20 = *reinterpret_cast<const float4*>(p20 + off);
      const float4 f11 = *reinterpret_cast<const float4*>(p11 + off);
      const float4 f21 = *reinterpret_cast<const float4*>(p21 + off);
      const int q = hh >> 1;
      a1[0][q].x += f10.x; a1[0][q].y += f10.y; a1[0][q].z += f10.z; a1[0][q].w += f10.w;
      a1[1][q].x += f11.x; a1[1][q].y += f11.y; a1[1][q].z += f11.z; a1[1][q].w += f11.w;
      a2[0][q].x += f20.x; a2[0][q].y += f20.y; a2[0][q].z += f20.z; a2[0][q].w += f20.w;
      a2[1][q].x += f21.x; a2[1][q].y += f21.y; a2[1][q].z += f21.z; a2[1][q].w += f21.w;
    }
  }

#pragma unroll
  for (int inp = 0; inp < 2; ++inp) {
    float4 (*A)[2] = inp ? a2 : a1;
    const float b0 = A[0][0].x + A[0][0].y, b1 = A[0][0].z + A[0][0].w;
    const float b2 = A[0][1].x + A[0][1].y, b3 = A[0][1].z + A[0][1].w;
    const float b4 = A[1][0].x + A[1][0].y, b5 = A[1][0].z + A[1][0].w;
    const float b6 = A[1][1].x + A[1][1].y, b7 = A[1][1].z + A[1][1].w;
    const float t0 = b0 + b1, t1 = b0 - b1, t2 = b2 + b3, t3 = b2 - b3;
    const float t4 = b4 + b5, t5 = b4 - b5, t6 = b6 + b7, t7 = b6 - b7;
    const float u0 = t0 + t2, u2 = t0 - t2, u1 = t1 + t3, u3 = t1 - t3;
    const float u4 = t4 + t6, u6 = t4 - t6, u5 = t5 + t7, u7 = t5 - t7;
    float* o = s + (size_t)inp * IS + (size_t)bc * M3 + v;
    o[0 * KS] = 0.125f * (u0 + u4);
    o[4 * KS] = 0.125f * (u0 - u4);
    o[1 * KS] = 0.125f * (u1 + u5);
    o[5 * KS] = 0.125f * (u1 - u5);
    o[2 * KS] = 0.125f * (u2 + u6);
    o[6 * KS] = 0.125f * (u2 - u6);
    o[3 * KS] = 0.125f * (u3 + u7);
    o[7 * KS] = 0.125f * (u3 - u7);
  }
}

// R14 fused mix+inv. 512 blocks (o 32 x vblk 16), 256 threads = voxels.
__global__ __launch_bounds__(256) void k_mixinv(const float* __restrict__ W1,
                                                const float* __restrict__ W2,
                                                const float* __restrict__ s,
                                                float* __restrict__ out) {
  const int bid  = blockIdx.x;
  const int vblk = bid & 15;         // bid%8 = vblk%8: XCD-pins the s-slice
  const int o    = bid >> 4;         // 0..31
  const int v = vblk * 256 + threadIdx.x;
  const float* ps  = s + v;
  const float* pW1 = W1 + (size_t)o * M3 + v;
  const float* pW2 = W2 + (size_t)o * M3 + v;

  float acc[4][8];                   // [b][m] inverse-WHT accumulators
#pragma unroll
  for (int b = 0; b < 4; ++b)
#pragma unroll
    for (int m = 0; m < 8; ++m) acc[b][m] = 0.f;

  for (int k = 0; k < 8; ++k) {      // runtime k keeps code compact
    const float* psk  = ps + (size_t)k * KS;
    const float* pw1k = pW1 + (size_t)k * 1024 * M3;
    const float* pw2k = pW2 + (size_t)k * 1024 * M3;
    float mix[4] = {0.f, 0.f, 0.f, 0.f};
#pragma unroll 2
    for (int i = 0; i < 32; ++i) {
      const float w1 = pw1k[(size_t)(i * 32) * M3];
      const float w2 = pw2k[(size_t)(i * 32) * M3];
#pragma unroll
      for (int b = 0; b < 4; ++b) {
        mix[b] += psk[(size_t)(b * 32 + i) * M3] * w1
                + psk[(size_t)IS + (size_t)(b * 32 + i) * M3] * w2;
      }
    }
#pragma unroll
    for (int m = 0; m < 8; ++m) {
      const float sgn = (__popc(k & m) & 1) ? -1.f : 1.f;
#pragma unroll
      for (int b = 0; b < 4; ++b) acc[b][m] += sgn * mix[b];
    }
  }

  // epilogue: old k_inv's verified store mapping, w[p][q][r] = 0.125*acc[m]
  const int z = v & 15, y = (v >> 4) & 15, x = v >> 8;
#pragma unroll
  for (int b = 0; b < 4; ++b) {
    float* base =
        out + ((((size_t)(b * 32 + o) * 64 + 4 * x) * 64 + 4 * y) * 64 + 4 * z);
#pragma unroll
    for (int dd = 0; dd < 4; ++dd) {
      const int p = dd >> 1;
#pragma unroll
      for (int hh = 0; hh < 4; ++hh) {
        const int q = hh >> 1;
        const float lo = 0.125f * acc[b][p * 4 + q * 2 + 0];
        const float hi = 0.125f * acc[b][p * 4 + q * 2 + 1];
        float4 f;
        f.x = lo; f.y = lo; f.z = hi; f.w = hi;
        *reinterpret_cast<float4*>(base + (dd * 64 + hh) * 64) = f;
      }
    }
  }
}

extern "C" void kernel_launch(void* const* d_in, const int* in_sizes, int n_in,
                              void* d_out, int out_size, void* d_ws, size_t ws_size,
                              hipStream_t stream) {
  const float* x1 = (const float*)d_in[0];
  const float* x2 = (const float*)d_in[1];
  const float* W1 = (const float*)d_in[2];
  const float* W2 = (const float*)d_in[3];
  float* out = (float*)d_out;
  float* s = (float*)d_ws;                 // 2*IS floats = 32 MiB
  k_fwd<<<2048, 256, 0, stream>>>(x1, x2, s);
  k_mixinv<<<512, 256, 0, stream>>>(W1, W2, s, out);
}